// Round 6
// baseline (514.991 us; speedup 1.0000x reference)
//
#include <hip/hip_runtime.h>
#include <stdint.h>

#define T_STEPS 512
#define CELLS   4096            // 64*64
#define EPB     32              // envs per rollout block (1 env per lane)
#define WPE     256             // packed words per env (16 cells/word)
#define WPAD    257             // LDS stride; word 256 = OOB sentinel (0)

// ---- Kernel 1: pack world (float walls+goals) to 2-bit codes in d_ws ----
// code: 2 = goal (g==10, priority), 1 = wall (w==1 && !goal), 0 = free
__device__ __forceinline__ uint32_t code4(float4 w, float4 g) {
    uint32_t b0 = (g.x == 10.0f) ? 2u : ((w.x == 1.0f) ? 1u : 0u);
    uint32_t b1 = (g.y == 10.0f) ? 2u : ((w.y == 1.0f) ? 1u : 0u);
    uint32_t b2 = (g.z == 10.0f) ? 2u : ((w.z == 1.0f) ? 1u : 0u);
    uint32_t b3 = (g.w == 10.0f) ? 2u : ((w.w == 1.0f) ? 1u : 0u);
    return b0 | (b1 << 2) | (b2 << 4) | (b3 << 6);   // 4 cells x 2 bits
}

__global__ __launch_bounds__(64) void pack_kernel(
    const float* __restrict__ world, uint32_t* __restrict__ packed)
{
    const int b = blockIdx.x;
    const int t = threadIdx.x;
    const float* wbase = world + (size_t)b * (2 * CELLS);
    const float* gbase = wbase + CELLS;
    #pragma unroll
    for (int h = 0; h < 4; ++h) {
        const int w  = h * 64 + t;     // word index, 16 cells per word
        const int c0 = w * 16;
        uint32_t word = 0;
        #pragma unroll
        for (int j = 0; j < 4; ++j) {
            float4 wf = *(const float4*)(wbase + c0 + 4 * j);
            float4 gf = *(const float4*)(gbase + c0 + 4 * j);
            word |= code4(wf, gf) << (8 * j);
        }
        packed[(size_t)b * WPE + w] = word;
    }
}

// ---- Kernel 2: lane-dense rollout, depth-4 speculative LDS probing ----
__global__ __launch_bounds__(64) void rollout_kernel(
    const float* __restrict__ s0,
    const int*   __restrict__ act,
    const uint32_t* __restrict__ packed,
    float* __restrict__ out,
    int B)
{
    __shared__ uint32_t lds[EPB * WPAD];   // 32896 B

    const int tid = threadIdx.x;
    const int b0  = blockIdx.x * EPB;

    // stage 32 envs' packed worlds (32 KB) into padded LDS
    for (int ee = 0; ee < EPB; ++ee) {
        uint4 v = *(const uint4*)(packed + (size_t)(b0 + ee) * WPE + tid * 4);
        const int base = ee * WPAD + tid * 4;
        lds[base]     = v.x;
        lds[base + 1] = v.y;
        lds[base + 2] = v.z;
        lds[base + 3] = v.w;
    }
    if (tid < EPB) lds[tid * WPAD + WPE] = 0u;   // OOB sentinel word = all-free
    __syncthreads();

    if (tid < EPB) {
        const int b = b0 + tid;
        float2 s = *(const float2*)(s0 + 2 * (size_t)b);
        int r = (int)s.x;
        int c = (int)s.y;
        int p = r * 64 + c;                     // invariant: p == r*64 + c
        const uint32_t* my = lds + tid * WPAD;

        // semantics (verified R3-R5, absmax 0): negative idx wraps (+4096,
        // NumPy normalization), then mode='fill' (NaN) for remaining OOB ->
        // free cell. Sentinel word (=0) implements the fill case.
        auto waddr = [&](int q) -> uint32_t {
            const int u = q + ((q >> 31) & CELLS);   // wrap negatives
            return ((unsigned)u < (unsigned)CELLS) ? ((unsigned)u >> 4) : (unsigned)WPE;
        };

        float* s_out = out + (size_t)b * (2 * (T_STEPS + 1));
        float* r_out = out + (size_t)B * (2 * (T_STEPS + 1)) + (size_t)b * (T_STEPS + 1);

        *(float2*)s_out = s;                    // s_full[:,0] = s0
        r_out[0] = 0.0f;                        // r_full[:,0] = 0

        const int4* ap = (const int4*)(act + (size_t)b * T_STEPS);
        int4 A0 = ap[0];
        int4 A1 = ap[1];
        int4 A2 = ap[2];
        for (int k = 0; k < T_STEPS / 4; ++k) {
            const int4 A3 = (k + 3 < T_STEPS / 4) ? ap[k + 3] : A0;  // 12 steps ahead
            const int a0 = A0.x, a1 = A0.y, a2 = A0.z, a3 = A0.w;
            // deltas: 1 -> r-1, 2 -> r+1, 3 -> c-1, 4 -> c+1, 0 -> stay
            const int d0r = (a0 == 1) ? -1 : ((a0 == 2) ? 1 : 0);
            const int d0c = (a0 == 3) ? -1 : ((a0 == 4) ? 1 : 0);
            const int d1r = (a1 == 1) ? -1 : ((a1 == 2) ? 1 : 0);
            const int d1c = (a1 == 3) ? -1 : ((a1 == 4) ? 1 : 0);
            const int d2r = (a2 == 1) ? -1 : ((a2 == 2) ? 1 : 0);
            const int d2c = (a2 == 3) ? -1 : ((a2 == 4) ? 1 : 0);
            const int d3r = (a3 == 1) ? -1 : ((a3 == 2) ? 1 : 0);
            const int d3c = (a3 == 3) ? -1 : ((a3 == 4) ? 1 : 0);
            const int e0 = d0r * 64 + d0c;
            const int e1 = d1r * 64 + d1c;
            const int e2 = d2r * 64 + d2c;
            const int e3 = d3r * 64 + d3c;

            // 15 speculative probes: step t+k reads p + subset(e0..e_{k-1}) + e_k.
            // All independent -> one batched ds_read group, one wait per 4 steps.
            const uint32_t w0     = my[waddr(p + e0)];
            const uint32_t w1_0   = my[waddr(p + e1)];
            const uint32_t w1_1   = my[waddr(p + e0 + e1)];
            const uint32_t w2_00  = my[waddr(p + e2)];
            const uint32_t w2_01  = my[waddr(p + e1 + e2)];
            const uint32_t w2_10  = my[waddr(p + e0 + e2)];
            const uint32_t w2_11  = my[waddr(p + e0 + e1 + e2)];
            const uint32_t w3_000 = my[waddr(p + e3)];
            const uint32_t w3_001 = my[waddr(p + e2 + e3)];
            const uint32_t w3_010 = my[waddr(p + e1 + e3)];
            const uint32_t w3_011 = my[waddr(p + e1 + e2 + e3)];
            const uint32_t w3_100 = my[waddr(p + e0 + e3)];
            const uint32_t w3_101 = my[waddr(p + e0 + e2 + e3)];
            const uint32_t w3_110 = my[waddr(p + e0 + e1 + e3)];
            const uint32_t w3_111 = my[waddr(p + e0 + e1 + e2 + e3)];

            const int t = k * 4;

            // ---- step t+0 ----
            int q = p + e0;
            int u = q + ((q >> 31) & CELLS);
            int cell = (w0 >> ((u & 15) << 1)) & 3;   // OOB -> sentinel word 0
            bool tk0 = (cell != 1);
            float rew = (cell == 2) ? 1.0f : ((cell == 1) ? -1.0f : -0.01f);
            p = tk0 ? q : p;  r = tk0 ? r + d0r : r;  c = tk0 ? c + d0c : c;
            *(float2*)(s_out + 2 * (t + 1)) = make_float2((float)r, (float)c);
            r_out[t + 1] = rew;

            // ---- step t+1 ----
            const uint32_t W1 = tk0 ? w1_1 : w1_0;
            q = p + e1;
            u = q + ((q >> 31) & CELLS);
            cell = (W1 >> ((u & 15) << 1)) & 3;
            bool tk1 = (cell != 1);
            rew = (cell == 2) ? 1.0f : ((cell == 1) ? -1.0f : -0.01f);
            p = tk1 ? q : p;  r = tk1 ? r + d1r : r;  c = tk1 ? c + d1c : c;
            *(float2*)(s_out + 2 * (t + 2)) = make_float2((float)r, (float)c);
            r_out[t + 2] = rew;

            // ---- step t+2 ----
            const uint32_t W2 = tk0 ? (tk1 ? w2_11 : w2_10)
                                    : (tk1 ? w2_01 : w2_00);
            q = p + e2;
            u = q + ((q >> 31) & CELLS);
            cell = (W2 >> ((u & 15) << 1)) & 3;
            bool tk2 = (cell != 1);
            rew = (cell == 2) ? 1.0f : ((cell == 1) ? -1.0f : -0.01f);
            p = tk2 ? q : p;  r = tk2 ? r + d2r : r;  c = tk2 ? c + d2c : c;
            *(float2*)(s_out + 2 * (t + 3)) = make_float2((float)r, (float)c);
            r_out[t + 3] = rew;

            // ---- step t+3 ----
            const uint32_t W3 = tk0 ? (tk1 ? (tk2 ? w3_111 : w3_110)
                                            : (tk2 ? w3_101 : w3_100))
                                    : (tk1 ? (tk2 ? w3_011 : w3_010)
                                            : (tk2 ? w3_001 : w3_000));
            q = p + e3;
            u = q + ((q >> 31) & CELLS);
            cell = (W3 >> ((u & 15) << 1)) & 3;
            bool tk3 = (cell != 1);
            rew = (cell == 2) ? 1.0f : ((cell == 1) ? -1.0f : -0.01f);
            p = tk3 ? q : p;  r = tk3 ? r + d3r : r;  c = tk3 ? c + d3c : c;
            *(float2*)(s_out + 2 * (t + 4)) = make_float2((float)r, (float)c);
            r_out[t + 4] = rew;

            A0 = A1; A1 = A2; A2 = A3;
        }
    }
}

extern "C" void kernel_launch(void* const* d_in, const int* in_sizes, int n_in,
                              void* d_out, int out_size, void* d_ws, size_t ws_size,
                              hipStream_t stream) {
    const float* s0    = (const float*)d_in[0];
    const int*   act   = (const int*)d_in[1];
    const float* world = (const float*)d_in[2];
    float*       out   = (float*)d_out;
    uint32_t*    packed = (uint32_t*)d_ws;     // needs B*256*4 = 8 MiB

    const int B = in_sizes[0] / 2;             // 8192

    pack_kernel<<<B, 64, 0, stream>>>(world, packed);
    rollout_kernel<<<B / EPB, 64, 0, stream>>>(s0, act, packed, out, B);
}

// Round 7
// 450.257 us; speedup vs baseline: 1.1438x; 1.1438x over previous
//
#include <hip/hip_runtime.h>
#include <stdint.h>

#define T_STEPS 512
#define CELLS   4096            // 64*64
#define EPB     32              // envs per rollout block (1 env per lane)
#define WPE     256             // packed world words per env (16 cells/word)
#define WPAD    257             // world LDS stride (odd -> conflict-light)
#define AWORDS  128             // packed action words per env (4 actions/word)
#define ASTRIDE 130             // action LDS stride (even for b64, %32==2 -> free 2-way)

// ---- Kernel 1: pack world (float walls+goals) to 2-bit codes in d_ws ----
// code: 2 = goal (g==10, priority), 1 = wall (w==1 && !goal), 0 = free
__device__ __forceinline__ uint32_t code4(float4 w, float4 g) {
    uint32_t b0 = (g.x == 10.0f) ? 2u : ((w.x == 1.0f) ? 1u : 0u);
    uint32_t b1 = (g.y == 10.0f) ? 2u : ((w.y == 1.0f) ? 1u : 0u);
    uint32_t b2 = (g.z == 10.0f) ? 2u : ((w.z == 1.0f) ? 1u : 0u);
    uint32_t b3 = (g.w == 10.0f) ? 2u : ((w.w == 1.0f) ? 1u : 0u);
    return b0 | (b1 << 2) | (b2 << 4) | (b3 << 6);   // 4 cells x 2 bits
}

__global__ __launch_bounds__(64) void pack_kernel(
    const float* __restrict__ world, uint32_t* __restrict__ packed)
{
    const int b = blockIdx.x;
    const int t = threadIdx.x;
    const float* wbase = world + (size_t)b * (2 * CELLS);
    const float* gbase = wbase + CELLS;
    #pragma unroll
    for (int h = 0; h < 4; ++h) {
        const int w  = h * 64 + t;     // word index, 16 cells per word
        const int c0 = w * 16;
        uint32_t word = 0;
        #pragma unroll
        for (int j = 0; j < 4; ++j) {
            float4 wf = *(const float4*)(wbase + c0 + 4 * j);
            float4 gf = *(const float4*)(gbase + c0 + 4 * j);
            word |= code4(wf, gf) << (8 * j);
        }
        packed[(size_t)b * WPE + w] = word;
    }
}

// ---- Kernel 2: lane-dense rollout; loop touches LDS only + pure stores ----
__global__ __launch_bounds__(64) void rollout_kernel(
    const float* __restrict__ s0,
    const int*   __restrict__ act,
    const uint32_t* __restrict__ packed,
    float* __restrict__ out,
    int B)
{
    __shared__ uint32_t wlds[EPB * WPAD];      // 32896 B: 2-bit worlds
    __shared__ uint32_t alds[EPB * ASTRIDE];   // 16640 B: byte-packed actions

    const int tid = threadIdx.x;
    const int b0  = blockIdx.x * EPB;

    // stage 32 envs' packed worlds (32 KB) into padded LDS
    for (int ee = 0; ee < EPB; ++ee) {
        uint4 v = *(const uint4*)(packed + (size_t)(b0 + ee) * WPE + tid * 4);
        const int base = ee * WPAD + tid * 4;
        wlds[base]     = v.x;
        wlds[base + 1] = v.y;
        wlds[base + 2] = v.z;
        wlds[base + 3] = v.w;
    }
    // stage 32 envs' actions as bytes: word w = actions[4w..4w+3]
    for (int ee = 0; ee < EPB; ++ee) {
        const int4* ap = (const int4*)(act + (size_t)(b0 + ee) * T_STEPS);
        const int4 x = ap[2 * tid];
        const int4 y = ap[2 * tid + 1];
        const uint32_t w0 = (uint32_t)(x.x & 255) | ((uint32_t)(x.y & 255) << 8)
                          | ((uint32_t)(x.z & 255) << 16) | ((uint32_t)(x.w & 255) << 24);
        const uint32_t w1 = (uint32_t)(y.x & 255) | ((uint32_t)(y.y & 255) << 8)
                          | ((uint32_t)(y.z & 255) << 16) | ((uint32_t)(y.w & 255) << 24);
        const int base = ee * ASTRIDE + 2 * tid;
        alds[base]     = w0;
        alds[base + 1] = w1;
    }
    __syncthreads();

    if (tid < EPB) {
        const int b = b0 + tid;
        float2 s = *(const float2*)(s0 + 2 * (size_t)b);
        int r = (int)s.x;
        int c = (int)s.y;
        int p = r * 64 + c;                     // invariant: p == r*64 + c
        const uint32_t* my    = wlds + tid * WPAD;
        const uint32_t* myact = alds + tid * ASTRIDE;

        // semantics (verified R3-R6, absmax 0): negative idx wraps (+4096,
        // NumPy normalization), then mode='fill' (NaN) for remaining OOB ->
        // free cell (code 0).
        auto lookup = [&](int q) -> int {
            const int idx = q + ((q < 0) ? CELLS : 0);
            const uint32_t wd = my[(idx >> 4) & (WPE - 1)];
            const int cell = (wd >> ((idx & 15) * 2)) & 3;
            return ((unsigned)idx < (unsigned)CELLS) ? cell : 0;
        };

        float* s_out = out + (size_t)b * (2 * (T_STEPS + 1));
        float* r_out = out + (size_t)B * (2 * (T_STEPS + 1)) + (size_t)b * (T_STEPS + 1);

        *(float2*)s_out = s;                    // s_full[:,0] = s0
        r_out[0] = 0.0f;                        // r_full[:,0] = 0

        uint32_t aw = myact[0];
        for (int k = 0; k < T_STEPS / 4; ++k) {
            const uint32_t aw_next = myact[k + 1];   // LDS prefetch, issues with probes
            const int a0 = aw & 255, a1 = (aw >> 8) & 255;
            const int a2 = (aw >> 16) & 255, a3 = (aw >> 24) & 255;
            const int as4[4] = {a0, a1, a2, a3};
            #pragma unroll
            for (int jj = 0; jj < 2; ++jj) {    // two speculative 2-step rounds
                const int t  = k * 4 + jj * 2;
                const int u0 = as4[2 * jj];
                const int u1 = as4[2 * jj + 1];
                // deltas: 1 -> r-1, 2 -> r+1, 3 -> c-1, 4 -> c+1, 0 -> stay
                const int d0r = (u0 == 1) ? -1 : ((u0 == 2) ? 1 : 0);
                const int d0c = (u0 == 3) ? -1 : ((u0 == 4) ? 1 : 0);
                const int d1r = (u1 == 1) ? -1 : ((u1 == 2) ? 1 : 0);
                const int d1c = (u1 == 3) ? -1 : ((u1 == 4) ? 1 : 0);
                const int e0 = d0r * 64 + d0c;
                const int e1 = d1r * 64 + d1c;
                // speculative probes: step t from p; step t+1 from {p, p+e0}
                const int q0  = p + e0;
                const int q10 = p + e1;
                const int q11 = q0 + e1;
                const int l0  = lookup(q0);
                const int l10 = lookup(q10);
                const int l11 = lookup(q11);
                // resolve step t
                const bool hw0  = (l0 == 1);
                const float rew0 = (l0 == 2) ? 1.0f : (hw0 ? -1.0f : -0.01f);
                const int p0  = hw0 ? p : q0;
                const int r0v = hw0 ? r : r + d0r;
                const int c0v = hw0 ? c : c + d0c;
                // resolve step t+1 from the matching speculative read
                const int l1 = hw0 ? l10 : l11;
                const bool hw1  = (l1 == 1);
                const float rew1 = (l1 == 2) ? 1.0f : (hw1 ? -1.0f : -0.01f);
                p = hw1 ? p0 : p0 + e1;
                r = hw1 ? r0v : r0v + d1r;
                c = hw1 ? c0v : c0v + d1c;
                *(float2*)(s_out + 2 * (t + 1)) = make_float2((float)r0v, (float)c0v);
                *(float2*)(s_out + 2 * (t + 2)) = make_float2((float)r, (float)c);
                r_out[t + 1] = rew0;
                r_out[t + 2] = rew1;
            }
            aw = aw_next;
        }
    }
}

extern "C" void kernel_launch(void* const* d_in, const int* in_sizes, int n_in,
                              void* d_out, int out_size, void* d_ws, size_t ws_size,
                              hipStream_t stream) {
    const float* s0    = (const float*)d_in[0];
    const int*   act   = (const int*)d_in[1];
    const float* world = (const float*)d_in[2];
    float*       out   = (float*)d_out;
    uint32_t*    packed = (uint32_t*)d_ws;     // needs B*256*4 = 8 MiB

    const int B = in_sizes[0] / 2;             // 8192

    pack_kernel<<<B, 64, 0, stream>>>(world, packed);
    rollout_kernel<<<B / EPB, 64, 0, stream>>>(s0, act, packed, out, B);
}

// Round 8
// 443.798 us; speedup vs baseline: 1.1604x; 1.0146x over previous
//
#include <hip/hip_runtime.h>
#include <stdint.h>

#define T_STEPS 512
#define CELLS   4096            // 64*64
#define EPB     32              // envs per rollout block (1 env per lane, mirrored)
#define WPE     256             // packed world words per env (16 cells/word)
#define WPAD    257             // world LDS stride
#define ASTRIDE 130             // action LDS stride (128 words used + slack)
#define SSTRIDE 66              // traj s-buf stride: 32 steps * 2 + 2 (even -> b64 ok)
#define RSTRIDE 33              // traj r-buf stride
#define CHUNK   32              // steps between coalesced flushes
#define NCHUNK  (T_STEPS / CHUNK)   // 16
#define KPC     (CHUNK / 4)         // 8 four-step k-iters per chunk

// ---- Kernel 1: pack world (float walls+goals) to 2-bit codes in d_ws ----
// code: 2 = goal (g==10, priority), 1 = wall (w==1 && !goal), 0 = free
__device__ __forceinline__ uint32_t code4(float4 w, float4 g) {
    uint32_t b0 = (g.x == 10.0f) ? 2u : ((w.x == 1.0f) ? 1u : 0u);
    uint32_t b1 = (g.y == 10.0f) ? 2u : ((w.y == 1.0f) ? 1u : 0u);
    uint32_t b2 = (g.z == 10.0f) ? 2u : ((w.z == 1.0f) ? 1u : 0u);
    uint32_t b3 = (g.w == 10.0f) ? 2u : ((w.w == 1.0f) ? 1u : 0u);
    return b0 | (b1 << 2) | (b2 << 4) | (b3 << 6);   // 4 cells x 2 bits
}

__global__ __launch_bounds__(64) void pack_kernel(
    const float* __restrict__ world, uint32_t* __restrict__ packed)
{
    const int b = blockIdx.x;
    const int t = threadIdx.x;
    const float* wbase = world + (size_t)b * (2 * CELLS);
    const float* gbase = wbase + CELLS;
    #pragma unroll
    for (int h = 0; h < 4; ++h) {
        const int w  = h * 64 + t;     // word index, 16 cells per word
        const int c0 = w * 16;
        uint32_t word = 0;
        #pragma unroll
        for (int j = 0; j < 4; ++j) {
            float4 wf = *(const float4*)(wbase + c0 + 4 * j);
            float4 gf = *(const float4*)(gbase + c0 + 4 * j);
            word |= code4(wf, gf) << (8 * j);
        }
        packed[(size_t)b * WPE + w] = word;
    }
}

// ---- Kernel 2: lane-dense rollout, LDS trajectory buffer + coalesced flush ----
__global__ __launch_bounds__(64) void rollout_kernel(
    const float* __restrict__ s0,
    const int*   __restrict__ act,
    const uint32_t* __restrict__ packed,
    float* __restrict__ out,
    int B)
{
    __shared__ uint32_t wlds[EPB * WPAD];      // 32896 B: 2-bit worlds
    __shared__ uint32_t alds[EPB * ASTRIDE];   // 16640 B: byte-packed actions
    __shared__ float    sbuf[EPB * SSTRIDE];   //  8448 B: 32-step s trajectory
    __shared__ float    rbuf[EPB * RSTRIDE];   //  4224 B: 32-step r trajectory
                                               // total 62208 B

    const int tid = threadIdx.x;
    const int b0  = blockIdx.x * EPB;

    // stage 32 envs' packed worlds (32 KB) into padded LDS
    for (int ee = 0; ee < EPB; ++ee) {
        uint4 v = *(const uint4*)(packed + (size_t)(b0 + ee) * WPE + tid * 4);
        const int base = ee * WPAD + tid * 4;
        wlds[base]     = v.x;
        wlds[base + 1] = v.y;
        wlds[base + 2] = v.z;
        wlds[base + 3] = v.w;
    }
    // stage 32 envs' actions as bytes: word w = actions[4w..4w+3]
    for (int ee = 0; ee < EPB; ++ee) {
        const int4* ap = (const int4*)(act + (size_t)(b0 + ee) * T_STEPS);
        const int4 x = ap[2 * tid];
        const int4 y = ap[2 * tid + 1];
        const uint32_t w0 = (uint32_t)(x.x & 255) | ((uint32_t)(x.y & 255) << 8)
                          | ((uint32_t)(x.z & 255) << 16) | ((uint32_t)(x.w & 255) << 24);
        const uint32_t w1 = (uint32_t)(y.x & 255) | ((uint32_t)(y.y & 255) << 8)
                          | ((uint32_t)(y.z & 255) << 16) | ((uint32_t)(y.w & 255) << 24);
        const int base = ee * ASTRIDE + 2 * tid;
        alds[base]     = w0;
        alds[base + 1] = w1;
    }
    __syncthreads();

    // every lane rolls out env e = tid & 31 (lanes 32-63 mirror 0-31: same
    // LDS reads broadcast, duplicate same-value LDS writes are benign)
    const int e = tid & (EPB - 1);
    const int b = b0 + e;
    float2 s = *(const float2*)(s0 + 2 * (size_t)b);
    int r = (int)s.x;
    int c = (int)s.y;
    int p = r * 64 + c;                     // invariant: p == r*64 + c
    const uint32_t* my    = wlds + e * WPAD;
    const uint32_t* myact = alds + e * ASTRIDE;

    // semantics (verified R3-R7, absmax 0): negative idx wraps (+4096, NumPy
    // normalization), then mode='fill' (NaN) for remaining OOB -> free cell.
    auto lookup = [&](int q) -> int {
        const int idx = q + ((q < 0) ? CELLS : 0);
        const uint32_t wd = my[(idx >> 4) & (WPE - 1)];
        const int cell = (wd >> ((idx & 15) * 2)) & 3;
        return ((unsigned)idx < (unsigned)CELLS) ? cell : 0;
    };

    float* const s_base = out;                               // [B][513][2]
    float* const r_base = out + (size_t)B * (2 * (T_STEPS + 1));  // [B][513]

    if (tid < EPB) {
        *(float2*)(s_base + (size_t)b * (2 * (T_STEPS + 1))) = s;  // s_full[:,0]
        r_base[(size_t)b * (T_STEPS + 1)] = 0.0f;                  // r_full[:,0]
    }

    uint32_t aw = myact[0];
    for (int chunk = 0; chunk < NCHUNK; ++chunk) {
        for (int k = 0; k < KPC; ++k) {
            const int kk = chunk * KPC + k;
            const uint32_t aw_next = myact[kk + 1];   // <=128, within ASTRIDE slack
            const int a0 = aw & 255, a1 = (aw >> 8) & 255;
            const int a2 = (aw >> 16) & 255, a3 = (aw >> 24) & 255;
            const int as4[4] = {a0, a1, a2, a3};
            #pragma unroll
            for (int jj = 0; jj < 2; ++jj) {    // two speculative 2-step rounds
                const int ls = k * 4 + jj * 2;  // local step within chunk
                const int u0 = as4[2 * jj];
                const int u1 = as4[2 * jj + 1];
                // deltas: 1 -> r-1, 2 -> r+1, 3 -> c-1, 4 -> c+1, 0 -> stay
                const int d0r = (u0 == 1) ? -1 : ((u0 == 2) ? 1 : 0);
                const int d0c = (u0 == 3) ? -1 : ((u0 == 4) ? 1 : 0);
                const int d1r = (u1 == 1) ? -1 : ((u1 == 2) ? 1 : 0);
                const int d1c = (u1 == 3) ? -1 : ((u1 == 4) ? 1 : 0);
                const int e0 = d0r * 64 + d0c;
                const int e1 = d1r * 64 + d1c;
                // speculative probes: step t from p; step t+1 from {p, p+e0}
                const int q0  = p + e0;
                const int q10 = p + e1;
                const int q11 = q0 + e1;
                const int l0  = lookup(q0);
                const int l10 = lookup(q10);
                const int l11 = lookup(q11);
                // resolve step t
                const bool hw0  = (l0 == 1);
                const float rew0 = (l0 == 2) ? 1.0f : (hw0 ? -1.0f : -0.01f);
                const int p0  = hw0 ? p : q0;
                const int r0v = hw0 ? r : r + d0r;
                const int c0v = hw0 ? c : c + d0c;
                // resolve step t+1 from the matching speculative read
                const int l1 = hw0 ? l10 : l11;
                const bool hw1  = (l1 == 1);
                const float rew1 = (l1 == 2) ? 1.0f : (hw1 ? -1.0f : -0.01f);
                p = hw1 ? p0 : p0 + e1;
                r = hw1 ? r0v : r0v + d1r;
                c = hw1 ? c0v : c0v + d1c;
                // buffer in LDS (coalesced global flush every CHUNK steps)
                *(float2*)(&sbuf[e * SSTRIDE + 2 * ls]) =
                    make_float2((float)r0v, (float)c0v);
                *(float2*)(&sbuf[e * SSTRIDE + 2 * ls + 2]) =
                    make_float2((float)r, (float)c);
                rbuf[e * RSTRIDE + ls]     = rew0;
                rbuf[e * RSTRIDE + ls + 1] = rew1;
            }
            aw = aw_next;
        }
        __syncthreads();   // 1 wave: cheap lgkmcnt drain + barrier
        // ---- coalesced flush: 64 contiguous floats per env (s), 32 (r) ----
        for (int ee = 0; ee < EPB; ++ee) {
            const float v = sbuf[ee * SSTRIDE + tid];
            s_base[(size_t)(b0 + ee) * (2 * (T_STEPS + 1)) + chunk * 64 + 2 + tid] = v;
        }
        for (int ee = 0; ee < EPB; ee += 2) {
            const int e2 = ee + (tid >> 5);
            const int j  = tid & 31;
            const float v = rbuf[e2 * RSTRIDE + j];
            r_base[(size_t)(b0 + e2) * (T_STEPS + 1) + chunk * 32 + 1 + j] = v;
        }
        __syncthreads();
    }
}

extern "C" void kernel_launch(void* const* d_in, const int* in_sizes, int n_in,
                              void* d_out, int out_size, void* d_ws, size_t ws_size,
                              hipStream_t stream) {
    const float* s0    = (const float*)d_in[0];
    const int*   act   = (const int*)d_in[1];
    const float* world = (const float*)d_in[2];
    float*       out   = (float*)d_out;
    uint32_t*    packed = (uint32_t*)d_ws;     // needs B*256*4 = 8 MiB

    const int B = in_sizes[0] / 2;             // 8192

    pack_kernel<<<B, 64, 0, stream>>>(world, packed);
    rollout_kernel<<<B / EPB, 64, 0, stream>>>(s0, act, packed, out, B);
}